// Round 13
// baseline (104.309 us; speedup 1.0000x reference)
//
#include <hip/hip_runtime.h>
#include <hip/hip_bf16.h>
#include <cmath>

#define HW   35200          // 200*176
#define CD   128            // C*D

typedef short bf16x8 __attribute__((ext_vector_type(8)));
typedef float f32x4  __attribute__((ext_vector_type(4)));

union Frag { unsigned u[4]; bf16x8 v; };   // 4 VGPR = 8 bf16

// ---- workspace float offsets ----
#define OFF_W1B   0         // w1b frag bf16 [3 kh][4 nt][64 lane][8 e] = 6144 bf16 = 3072 f
#define OFF_W2B   3072      // w2b frag bf16 [2 kh][2 nt][64][8]        = 2048 bf16 = 1024 f
#define OFF_TD    4096      // tD[d][o] fp32 (b1,be1,BN folded)           128 f
#define OFF_B2F   4224      // 32 f
#define OFF_W3F   4256      // 32 f
#define OFF_PE    4288      // peHW[hw][32] bf16 = 1126400 bf16 = 563200 f
#define OFF_F0B   567488    // f0b bf16 [4][32][HW][4] = 18022400 bf16 = 9011200 f
#define OFF_F1B   9578688   // f1b bf16 same size

__device__ __forceinline__ float lrelu(float v) { return v >= 0.f ? v : 0.01f * v; }
__device__ __forceinline__ unsigned short f2bf(float f) {
  union { __hip_bfloat16 h; unsigned short u; } c;
  c.h = __float2bfloat16(f);
  return c.u;
}
__device__ __forceinline__ unsigned pack2bf(float lo, float hi) {
  union { __hip_bfloat162 h2; unsigned u; } c;
  c.h2 = __float22bfloat162_rn(float2{lo, hi});
  return c.u;
}
__device__ __forceinline__ float bflo(unsigned u) { return __uint_as_float(u << 16); }
__device__ __forceinline__ float bfhi(unsigned u) { return __uint_as_float(u & 0xffff0000u); }

// ---------------- setup: BN-folded bf16 weight frags, tD, PE table ----------------
__global__ void setup_kernel(const float* __restrict__ w1, const float* __restrict__ b1,
                             const float* __restrict__ g1, const float* __restrict__ be1,
                             const float* __restrict__ w2, const float* __restrict__ b2,
                             const float* __restrict__ g2, const float* __restrict__ be2,
                             const float* __restrict__ w3, const float* __restrict__ b3,
                             float* __restrict__ ws) {
  const float RS = rsqrtf(1.0f + 1e-5f);
  unsigned short* w1b = (unsigned short*)(ws + OFF_W1B);
  unsigned short* w2b = (unsigned short*)(ws + OFF_W2B);
  unsigned short* pe  = (unsigned short*)(ws + OFF_PE);
  int i = blockIdx.x * blockDim.x + threadIdx.x;
  if (i < 6144) {                  // w1b: B[k][n], k=kh*32+(l>>4)*8+e, n=nt*16+(l&15)
    int e = i & 7, l = (i >> 3) & 63, nt = (i >> 9) & 3, kh = i >> 11;
    int n = nt * 16 + (l & 15);
    int k = kh * 32 + (l >> 4) * 8 + e;
    int col = (kh < 2) ? k : (80 + (k - 64));   // PE slots s=k-64 map to w1 cols 80..111
    w1b[i] = f2bf(w1[n * 112 + col] * (g1[n] * RS));
    return;
  }
  i -= 6144;
  if (i < 2048) {                  // w2b
    int e = i & 7, l = (i >> 3) & 63, nt = (i >> 9) & 1, kh = i >> 10;
    int n = nt * 16 + (l & 15);
    int k = kh * 32 + (l >> 4) * 8 + e;
    w2b[i] = f2bf(w2[n * 64 + k] * (g2[n] * RS));
    return;
  }
  i -= 2048;
  if (i < 128) {                   // tD[d][o] = s1*(b1 + w1[64..79]·encD(d)) + be1
    int d = i >> 6, o = i & 63;
    float a = 0.f;
    for (int j = 0; j < 8; ++j) {
      float dv = expf((float)(2 * j) * (-0.5756462732485115f));
      float t  = (float)d * dv;
      a += w1[o * 112 + 64 + j] * sinf(t) + w1[o * 112 + 72 + j] * cosf(t);
    }
    ws[OFF_TD + d * 64 + o] = (g1[o] * RS) * (b1[o] + a) + be1[o];
    return;
  }
  i -= 128;
  if (i < 32) { ws[OFF_B2F + i] = b2[i] * (g2[i] * RS) + be2[i]; return; }
  i -= 32;
  if (i < 32) { ws[OFF_W3F + i] = w3[i]; return; }
  i -= 32;
  if (i < 563200) {                // peHW[hw][32]: slots 0-7 sinH,8-15 cosH,16-23 sinW,24-31 cosW
    int hw = i >> 4, j = i & 15;
    int h = hw / 176, w = hw - h * 176;
    int jj = j & 7;
    float dv = expf((float)(2 * jj) * (-0.5756462732485115f));
    if (j < 8) {
      float t = (float)h * dv;
      pe[hw * 32 + jj]      = f2bf(sinf(t));
      pe[hw * 32 + 8 + jj]  = f2bf(cosf(t));
    } else {
      float t = (float)w * dv;
      pe[hw * 32 + 16 + jj] = f2bf(sinf(t));
      pe[hw * 32 + 24 + jj] = f2bf(cosf(t));
    }
  }
}

// ---------------- pass 1: ONE-WAVE blocks; wave-local MFMA MLP on 16 px ----------------
// Block = 1 wave = 64 threads, 16 px, both depths. Lane (g=l>>4, li=l&15):
// 4 g-lanes share px=hw0+li, each owns k-slice g*8..g*8+7. Zero barriers; 4 KB LDS.
// Grid 2200 x 4 x 2 = 17600 independent waves -> max TLP for latency hiding.
__global__ __launch_bounds__(64)
void mlp_kernel(const float* __restrict__ x0, const float* __restrict__ x1,
                const float* __restrict__ wtab,
                unsigned short* __restrict__ f0b, unsigned short* __restrict__ f1b) {
  __shared__ alignas(16) unsigned short Hs[8 * 32 * 8];   // [kgrp][d*16+pxm][8] = 4 KB

  const int lane = threadIdx.x & 63;
  const int g    = lane >> 4;          // k-subgroup 0..3
  const int li   = lane & 15;          // px-in-tile 0..15
  const int n    = blockIdx.y;
  const int inp  = blockIdx.z;
  const int hw0  = blockIdx.x * 16;
  const int px   = hw0 + li;
  const float* xn = (inp ? x1 : x0) + (size_t)n * CD * HW;
  unsigned short* dst = inp ? f1b : f0b;
  const unsigned short* w1bu = (const unsigned short*)(wtab + OFF_W1B);
  const unsigned short* w2bu = (const unsigned short*)(wtab + OFF_W2B);
  const unsigned short* peg  = (const unsigned short*)(wtab + OFF_PE);

  // ---- direct A-fragment loads: x fp32 + PE uint4 ----
  float xf[2][2][8];                   // [d][kh][e]
#pragma unroll
  for (int d = 0; d < 2; ++d)
#pragma unroll
    for (int kh = 0; kh < 2; ++kh)
#pragma unroll
      for (int e = 0; e < 8; ++e) {
        const int c = kh * 32 + g * 8 + e;
        xf[d][kh][e] = xn[(size_t)(c * 2 + d) * HW + px];
      }
  const uint4 pev = *(const uint4*)(peg + (size_t)px * 32 + g * 8);

  // pack to bf16 fragments (kept live through the f-store)
  Frag xb[2][2];
#pragma unroll
  for (int d = 0; d < 2; ++d)
#pragma unroll
    for (int kh = 0; kh < 2; ++kh)
#pragma unroll
      for (int q = 0; q < 4; ++q)
        xb[d][kh].u[q] = pack2bf(xf[d][kh][2 * q], xf[d][kh][2 * q + 1]);
  Frag pf;
  pf.u[0] = pev.x; pf.u[1] = pev.y; pf.u[2] = pev.z; pf.u[3] = pev.w;

  // ---- layer 1: 2 tiles (d) x K=96 x N=64; acc init = tD ----
  f32x4 acc[2][4];
#pragma unroll
  for (int d = 0; d < 2; ++d)
#pragma unroll
    for (int nt = 0; nt < 4; ++nt) {
      const float tdv = wtab[OFF_TD + d * 64 + nt * 16 + li];
      acc[d][nt] = (f32x4){tdv, tdv, tdv, tdv};
    }
#pragma unroll
  for (int kh = 0; kh < 2; ++kh)
#pragma unroll
    for (int nt = 0; nt < 4; ++nt) {
      const bf16x8 b = *(const bf16x8*)&w1bu[(unsigned)((kh * 4 + nt) * 64 + lane) * 8];
      acc[0][nt] = __builtin_amdgcn_mfma_f32_16x16x32_bf16(xb[0][kh].v, b, acc[0][nt], 0, 0, 0);
      acc[1][nt] = __builtin_amdgcn_mfma_f32_16x16x32_bf16(xb[1][kh].v, b, acc[1][nt], 0, 0, 0);
    }
#pragma unroll
  for (int nt = 0; nt < 4; ++nt) {
    const bf16x8 b = *(const bf16x8*)&w1bu[(unsigned)((8 + nt) * 64 + lane) * 8];
    acc[0][nt] = __builtin_amdgcn_mfma_f32_16x16x32_bf16(pf.v, b, acc[0][nt], 0, 0, 0);
    acc[1][nt] = __builtin_amdgcn_mfma_f32_16x16x32_bf16(pf.v, b, acc[1][nt], 0, 0, 0);
  }

  // ---- lrelu + h1 -> Hs (same-wave; lgkmcnt orders, no barrier) ----
#pragma unroll
  for (int d = 0; d < 2; ++d)
#pragma unroll
    for (int nt = 0; nt < 4; ++nt)
#pragma unroll
      for (int r = 0; r < 4; ++r) {
        const int o   = nt * 16 + li;          // output channel (C col)
        const int row = d * 16 + g * 4 + r;    // pixel row (C row)
        Hs[(unsigned)((o >> 3) * 32 + row) * 8 + (o & 7)] = f2bf(lrelu(acc[d][nt][r]));
      }

  // ---- layer 2: K=64 x N=32 ----
  f32x4 acc2[2][2];
#pragma unroll
  for (int nt = 0; nt < 2; ++nt) {
    const float bv = wtab[OFF_B2F + nt * 16 + li];
    acc2[0][nt] = (f32x4){bv, bv, bv, bv};
    acc2[1][nt] = acc2[0][nt];
  }
#pragma unroll
  for (int kh = 0; kh < 2; ++kh) {
    const bf16x8 a0 = *(const bf16x8*)&Hs[(unsigned)((kh * 4 + g) * 32 + 0 * 16 + li) * 8];
    const bf16x8 a1 = *(const bf16x8*)&Hs[(unsigned)((kh * 4 + g) * 32 + 1 * 16 + li) * 8];
#pragma unroll
    for (int nt = 0; nt < 2; ++nt) {
      const bf16x8 b = *(const bf16x8*)&w2bu[(unsigned)((kh * 2 + nt) * 64 + lane) * 8];
      acc2[0][nt] = __builtin_amdgcn_mfma_f32_16x16x32_bf16(a0, b, acc2[0][nt], 0, 0, 0);
      acc2[1][nt] = __builtin_amdgcn_mfma_f32_16x16x32_bf16(a1, b, acc2[1][nt], 0, 0, 0);
    }
  }

  // ---- layer 3 + 16-lane reduce + in-wave softmax (b3 cancels) ----
  const float w3a = wtab[OFF_W3F + li];
  const float w3b = wtab[OFF_W3F + 16 + li];
  float wt0[4], wt1[4];
#pragma unroll
  for (int r = 0; r < 4; ++r) {
    float p0 = w3a * lrelu(acc2[0][0][r]) + w3b * lrelu(acc2[0][1][r]);   // d0 logit, pxm=g*4+r
    float p1 = w3a * lrelu(acc2[1][0][r]) + w3b * lrelu(acc2[1][1][r]);   // d1 logit
    p0 += __shfl_xor(p0, 1); p0 += __shfl_xor(p0, 2);
    p0 += __shfl_xor(p0, 4); p0 += __shfl_xor(p0, 8);
    p1 += __shfl_xor(p1, 1); p1 += __shfl_xor(p1, 2);
    p1 += __shfl_xor(p1, 4); p1 += __shfl_xor(p1, 8);
    wt0[r] = 1.f / (1.f + expf(p1 - p0));
    wt1[r] = 1.f / (1.f + expf(p0 - p1));
  }

  // ---- wt distribution: lane's px=li owned by group li>>2, slot li&3 ----
  const int src = (li >> 2) << 4;
  float a0 = __shfl(wt0[0], src), b0 = __shfl(wt1[0], src);
  float a1 = __shfl(wt0[1], src), b1v = __shfl(wt1[1], src);
  float a2 = __shfl(wt0[2], src), b2v = __shfl(wt1[2], src);
  float a3 = __shfl(wt0[3], src), b3v = __shfl(wt1[3], src);
  const int rs = li & 3;
  const float w0  = (rs == 0) ? a0 : (rs == 1) ? a1 : (rs == 2) ? a2 : a3;
  const float w1v = (rs == 0) ? b0 : (rs == 1) ? b1v : (rs == 2) ? b2v : b3v;

  // ---- f-store from the bf16 A-fragment registers (4 g-lanes cover k=0..31 for px) ----
#pragma unroll
  for (int kh = 0; kh < 2; ++kh)
#pragma unroll
    for (int j = 0; j < 4; ++j) {
      const int k = kh * 16 + g * 4 + j;        // channel-pair index; c0=2k, c1=2k+1
      const unsigned ua = xb[0][kh].u[j];       // (c0,d0) lo | (c1,d0) hi
      const unsigned ub = xb[1][kh].u[j];       // (c0,d1) lo | (c1,d1) hi
      uint2 pk;
      pk.x = pack2bf(bflo(ua) * w0, bflo(ub) * w1v);
      pk.y = pack2bf(bfhi(ua) * w0, bfhi(ub) * w1v);
      *(uint2*)&dst[(((size_t)n * 32 + k) * HW + px) * 4] = pk;
    }
}

// ---------------- pass 2: pure memory — out = max(f0, bilinear(rot(f1))) ----------------
__global__ __launch_bounds__(256)
void gather_max_kernel(const unsigned short* __restrict__ f0b,
                       const unsigned short* __restrict__ f1b,
                       const float* __restrict__ tp,
                       float* __restrict__ out) {
  // bijective XCD swizzle over 550 tiles (q=68, r=6)
  const int orig = blockIdx.x;
  const int xcd = orig & 7, idx = orig >> 3;
  const int tile = (xcd < 6 ? xcd * 69 : 6 * 69 + (xcd - 6) * 68) + idx;

  const int tix = threadIdx.x;
  const int px  = tix & 63;
  const int q   = tix >> 6;
  const int n   = blockIdx.y;
  const int hw  = tile * 64 + px;
  const int h   = hw / 176;
  const int w   = hw - h * 176;

  const float thp = tp[n * 2 + 0], thc = tp[n * 2 + 1];
  const float gx = 0.2f + 0.4f * (float)w;
  const float gy = -39.8f + 0.4f * (float)h;
  const float c1 = cosf(thc),  s1v = sinf(thc);
  const float p1x = gx * c1 - gy * s1v;
  const float p1y = gx * s1v + gy * c1;
  const float c2 = cosf(-thp), s2v = sinf(-thp);
  const float p2x = p1x * c2 - p1y * s2v;
  const float p2y = p1x * s2v + p1y * c2;
  const float xi = p2x / 0.05f / 8.f;
  const float yi = (p2y - (-40.f)) / 0.05f / 8.f;

  const float xf = floorf(xi), yf = floorf(yi);
  const int x0i = (int)xf, y0i = (int)yf;
  const int x0c = min(max(x0i,     0), 175);
  const int x1c = min(max(x0i + 1, 0), 175);
  const int y0c = min(max(y0i,     0), 199);
  const int y1c = min(max(y0i + 1, 0), 199);
  const float x0f = (float)x0c, x1f = (float)x1c;
  const float y0f = (float)y0c, y1f = (float)y1c;
  const float wa = (x1f - xi) * (y1f - yi);
  const float wb = (x1f - xi) * (yi - y0f);
  const float wc = (xi - x0f) * (y1f - yi);
  const float wd = (xi - x0f) * (yi - y0f);
  const int ta = y0c * 176 + x0c, tb = y1c * 176 + x0c;
  const int tc = y0c * 176 + x1c, td = y1c * 176 + x1c;

#pragma unroll
  for (int i = 0; i < 8; ++i) {
    const int k = q * 8 + i;
    const int cd0 = k * 4;
    const unsigned short* fp1 = f1b + ((size_t)n * 32 + k) * HW * 4;
    const uint2 Ia = *(const uint2*)(fp1 + (size_t)ta * 4);
    const uint2 Ib = *(const uint2*)(fp1 + (size_t)tb * 4);
    const uint2 Ic = *(const uint2*)(fp1 + (size_t)tc * 4);
    const uint2 Id = *(const uint2*)(fp1 + (size_t)td * 4);
    float4 sv;
    sv.x = bflo(Ia.x) * wa + bflo(Ib.x) * wb + bflo(Ic.x) * wc + bflo(Id.x) * wd;
    sv.y = bfhi(Ia.x) * wa + bfhi(Ib.x) * wb + bfhi(Ic.x) * wc + bfhi(Id.x) * wd;
    sv.z = bflo(Ia.y) * wa + bflo(Ib.y) * wb + bflo(Ic.y) * wc + bflo(Id.y) * wd;
    sv.w = bfhi(Ia.y) * wa + bfhi(Ib.y) * wb + bfhi(Ic.y) * wc + bfhi(Id.y) * wd;

    const uint2 F0 = *(const uint2*)(f0b + (((size_t)n * 32 + k) * HW + hw) * 4);

    float* op = out + ((size_t)n * CD + cd0) * HW + hw;
    op[0]              = fmaxf(bflo(F0.x), sv.x);
    op[HW]             = fmaxf(bfhi(F0.x), sv.y);
    op[2 * (size_t)HW] = fmaxf(bflo(F0.y), sv.z);
    op[3 * (size_t)HW] = fmaxf(bfhi(F0.y), sv.w);
  }
}

extern "C" void kernel_launch(void* const* d_in, const int* in_sizes, int n_in,
                              void* d_out, int out_size, void* d_ws, size_t ws_size,
                              hipStream_t stream) {
  const float* x0  = (const float*)d_in[0];
  const float* x1  = (const float*)d_in[1];
  const float* tp  = (const float*)d_in[2];
  const float* w1  = (const float*)d_in[3];
  const float* b1  = (const float*)d_in[4];
  const float* g1  = (const float*)d_in[5];
  const float* be1 = (const float*)d_in[6];
  const float* w2  = (const float*)d_in[7];
  const float* b2  = (const float*)d_in[8];
  const float* g2  = (const float*)d_in[9];
  const float* be2 = (const float*)d_in[10];
  const float* w3  = (const float*)d_in[11];
  const float* b3  = (const float*)d_in[12];
  float* ws = (float*)d_ws;
  unsigned short* f0b = (unsigned short*)(ws + OFF_F0B);
  unsigned short* f1b = (unsigned short*)(ws + OFF_F1B);

  setup_kernel<<<2233, 256, 0, stream>>>(w1, b1, g1, be1, w2, b2, g2, be2, w3, b3, ws);

  dim3 g1d(2200, 4, 2);  // 16 px per 1-wave block, n, input
  mlp_kernel<<<g1d, 64, 0, stream>>>(x0, x1, ws, f0b, f1b);

  dim3 g2d(550, 4);      // 64 px x 4 channel-quarters, n
  gather_max_kernel<<<g2d, 256, 0, stream>>>(f0b, f1b, tp, (float*)d_out);
}

// Round 14
// 83.272 us; speedup vs baseline: 1.2526x; 1.2526x over previous
//
#include <hip/hip_runtime.h>
#include <hip/hip_bf16.h>
#include <cmath>

#define HW   35200          // 200*176
#define CD   128            // C*D

typedef short bf16x8 __attribute__((ext_vector_type(8)));
typedef float f32x4  __attribute__((ext_vector_type(4)));
typedef unsigned int u32;

union Frag { unsigned u[4]; bf16x8 v; };   // 4 VGPR = 8 bf16

// async global->LDS: 16B per lane, per-lane global addr, wave-uniform LDS base
#define GLD16(srcp, dstp) \
  __builtin_amdgcn_global_load_lds((const __attribute__((address_space(1))) u32*)(const void*)(srcp), \
                                   (__attribute__((address_space(3))) u32*)(void*)(dstp), 16, 0, 0)

// ---- workspace float offsets ----
#define OFF_W1B   0         // w1b frag bf16 [3 kh][4 nt][64 lane][8 e] = 6144 bf16 = 3072 f
#define OFF_W2B   3072      // w2b frag bf16 [2 kh][2 nt][64][8]        = 2048 bf16 = 1024 f
#define OFF_TD    4096      // tD[d][o] fp32 (b1,be1,BN folded)           128 f
#define OFF_B2F   4224      // 32 f
#define OFF_W3F   4256      // 32 f
#define OFF_PE    4288      // peHW[hw][32] bf16 = 1126400 bf16 = 563200 f
#define OFF_F0B   567488    // f0b bf16 [4][32][HW][4] = 18022400 bf16 = 9011200 f
#define OFF_F1B   9578688   // f1b bf16 same size

__device__ __forceinline__ float lrelu(float v) { return v >= 0.f ? v : 0.01f * v; }
__device__ __forceinline__ unsigned short f2bf(float f) {
  union { __hip_bfloat16 h; unsigned short u; } c;
  c.h = __float2bfloat16(f);
  return c.u;
}
__device__ __forceinline__ unsigned pack2bf(float lo, float hi) {
  union { __hip_bfloat162 h2; unsigned u; } c;
  c.h2 = __float22bfloat162_rn(float2{lo, hi});
  return c.u;
}
__device__ __forceinline__ float bflo(unsigned u) { return __uint_as_float(u << 16); }
__device__ __forceinline__ float bfhi(unsigned u) { return __uint_as_float(u & 0xffff0000u); }

// ---------------- setup: BN-folded bf16 weight frags, tD, PE table ----------------
__global__ void setup_kernel(const float* __restrict__ w1, const float* __restrict__ b1,
                             const float* __restrict__ g1, const float* __restrict__ be1,
                             const float* __restrict__ w2, const float* __restrict__ b2,
                             const float* __restrict__ g2, const float* __restrict__ be2,
                             const float* __restrict__ w3, const float* __restrict__ b3,
                             float* __restrict__ ws) {
  const float RS = rsqrtf(1.0f + 1e-5f);
  unsigned short* w1b = (unsigned short*)(ws + OFF_W1B);
  unsigned short* w2b = (unsigned short*)(ws + OFF_W2B);
  unsigned short* pe  = (unsigned short*)(ws + OFF_PE);
  int i = blockIdx.x * blockDim.x + threadIdx.x;
  if (i < 6144) {                  // w1b: B[k][n], k=kh*32+(l>>4)*8+e, n=nt*16+(l&15)
    int e = i & 7, l = (i >> 3) & 63, nt = (i >> 9) & 3, kh = i >> 11;
    int n = nt * 16 + (l & 15);
    int k = kh * 32 + (l >> 4) * 8 + e;
    int col = (kh < 2) ? k : (80 + (k - 64));   // PE slots s=k-64 map to w1 cols 80..111
    w1b[i] = f2bf(w1[n * 112 + col] * (g1[n] * RS));
    return;
  }
  i -= 6144;
  if (i < 2048) {                  // w2b
    int e = i & 7, l = (i >> 3) & 63, nt = (i >> 9) & 1, kh = i >> 10;
    int n = nt * 16 + (l & 15);
    int k = kh * 32 + (l >> 4) * 8 + e;
    w2b[i] = f2bf(w2[n * 64 + k] * (g2[n] * RS));
    return;
  }
  i -= 2048;
  if (i < 128) {                   // tD[d][o] = s1*(b1 + w1[64..79]·encD(d)) + be1
    int d = i >> 6, o = i & 63;
    float a = 0.f;
    for (int j = 0; j < 8; ++j) {
      float dv = expf((float)(2 * j) * (-0.5756462732485115f));
      float t  = (float)d * dv;
      a += w1[o * 112 + 64 + j] * sinf(t) + w1[o * 112 + 72 + j] * cosf(t);
    }
    ws[OFF_TD + d * 64 + o] = (g1[o] * RS) * (b1[o] + a) + be1[o];
    return;
  }
  i -= 128;
  if (i < 32) { ws[OFF_B2F + i] = b2[i] * (g2[i] * RS) + be2[i]; return; }
  i -= 32;
  if (i < 32) { ws[OFF_W3F + i] = w3[i]; return; }
  i -= 32;
  if (i < 563200) {                // peHW[hw][32]: slots 0-7 sinH,8-15 cosH,16-23 sinW,24-31 cosW
    int hw = i >> 4, j = i & 15;
    int h = hw / 176, w = hw - h * 176;
    int jj = j & 7;
    float dv = expf((float)(2 * jj) * (-0.5756462732485115f));
    if (j < 8) {
      float t = (float)h * dv;
      pe[hw * 32 + jj]      = f2bf(sinf(t));
      pe[hw * 32 + 8 + jj]  = f2bf(cosf(t));
    } else {
      float t = (float)w * dv;
      pe[hw * 32 + 16 + jj] = f2bf(sinf(t));
      pe[hw * 32 + 24 + jj] = f2bf(cosf(t));
    }
  }
}

// ---------------- pass 1: async-DMA staged MFMA MLP; writes fXb = x*wt (bf16) ----------------
// Block: 64 px, 4 waves. Staging: 32 global_load_lds (x fp32 -> As[128 plane][64 px])
// + 4 (PE bf16 -> Pe[64 px][32]); fire-and-forget DMA, one barrier.
// Wave wv owns px [16wv,16wv+16) x both depths (R10 mapping): in-wave softmax,
// wave-private Hs rows (overlaying dead As after barrier 2), register f-store.
__global__ __launch_bounds__(256)
void mlp_kernel(const float* __restrict__ x0, const float* __restrict__ x1,
                const float* __restrict__ wtab,
                unsigned short* __restrict__ f0b, unsigned short* __restrict__ f1b) {
  __shared__ alignas(16) unsigned char Sm[36864];
  float*          Asf = (float*)Sm;                     // [0,32768): x fp32 [plane][64]
  unsigned short* Hs  = (unsigned short*)Sm;            // overlay after barrier 2, 16 KB
  unsigned short* Pe  = (unsigned short*)(Sm + 32768);  // [64 px][32] bf16, 4 KB

  const int t    = threadIdx.x;
  const int lane = t & 63;
  const int wv   = __builtin_amdgcn_readfirstlane(t >> 6);
  const int g    = lane >> 4;          // k-subgroup 0..3
  const int li   = lane & 15;          // 0..15
  const int n    = blockIdx.y;
  const int inp  = blockIdx.z;
  const int hw0  = blockIdx.x * 64;
  const int pxl  = wv * 16 + li;       // this lane's local px
  const int px   = hw0 + pxl;
  const float* xn = (inp ? x1 : x0) + (size_t)n * CD * HW;
  unsigned short* dst = inp ? f1b : f0b;
  const unsigned short* w1bu = (const unsigned short*)(wtab + OFF_W1B);
  const unsigned short* w2bu = (const unsigned short*)(wtab + OFF_W2B);
  const unsigned short* peg  = (const unsigned short*)(wtab + OFF_PE);

  // ---- stage: 32 x-insts (4 planes each) + 4 PE-insts, round-robin over waves ----
  // x inst m: lane l -> plane 4m+(l>>4), px quarter (l&15)*4; dest Sm + m*1024 (linear)
#pragma unroll
  for (int m = wv; m < 32; m += 4)
    GLD16(xn + (size_t)(4 * m + g) * HW + hw0 + li * 4, Sm + m * 1024);
  // PE inst wv: lane l -> px wv*16+(l>>2), 16B quarter (l&3); dest Pe + wv*1024
  GLD16(peg + (size_t)(hw0 + wv * 16 + (lane >> 2)) * 32 + (lane & 3) * 8,
        (unsigned char*)Pe + wv * 1024);
  __syncthreads();                                     // [1] DMA drained (vmcnt 0 + barrier)

  // ---- build A-frags from LDS: x fp32 -> cvt_pk bf16; PE bf16 direct b128 ----
  float xv[2][2][8];
#pragma unroll
  for (int d = 0; d < 2; ++d)
#pragma unroll
    for (int kh = 0; kh < 2; ++kh)
#pragma unroll
      for (int e = 0; e < 8; ++e) {
        const int plane = (kh * 32 + g * 8 + e) * 2 + d;
        xv[d][kh][e] = Asf[plane * 64 + pxl];
      }
  Frag pf;
  pf.v = *(const bf16x8*)&Pe[pxl * 32 + g * 8];

  Frag xb[2][2];
#pragma unroll
  for (int d = 0; d < 2; ++d)
#pragma unroll
    for (int kh = 0; kh < 2; ++kh)
#pragma unroll
      for (int q = 0; q < 4; ++q)
        xb[d][kh].u[q] = pack2bf(xv[d][kh][2 * q], xv[d][kh][2 * q + 1]);
  __syncthreads();                                     // [2] As fp32 dead -> Hs overlay safe

  // ---- layer 1: 2 tiles (d) x K=96 x N=64; acc init = tD ----
  f32x4 acc[2][4];
#pragma unroll
  for (int d = 0; d < 2; ++d)
#pragma unroll
    for (int nt = 0; nt < 4; ++nt) {
      const float tdv = wtab[OFF_TD + d * 64 + nt * 16 + li];
      acc[d][nt] = (f32x4){tdv, tdv, tdv, tdv};
    }
#pragma unroll
  for (int kh = 0; kh < 2; ++kh)
#pragma unroll
    for (int nt = 0; nt < 4; ++nt) {
      const bf16x8 b = *(const bf16x8*)&w1bu[(unsigned)((kh * 4 + nt) * 64 + lane) * 8];
      acc[0][nt] = __builtin_amdgcn_mfma_f32_16x16x32_bf16(xb[0][kh].v, b, acc[0][nt], 0, 0, 0);
      acc[1][nt] = __builtin_amdgcn_mfma_f32_16x16x32_bf16(xb[1][kh].v, b, acc[1][nt], 0, 0, 0);
    }
#pragma unroll
  for (int nt = 0; nt < 4; ++nt) {
    const bf16x8 b = *(const bf16x8*)&w1bu[(unsigned)((8 + nt) * 64 + lane) * 8];
    acc[0][nt] = __builtin_amdgcn_mfma_f32_16x16x32_bf16(pf.v, b, acc[0][nt], 0, 0, 0);
    acc[1][nt] = __builtin_amdgcn_mfma_f32_16x16x32_bf16(pf.v, b, acc[1][nt], 0, 0, 0);
  }

  // ---- lrelu + h1 -> Hs (wave-private rows d*64+pxl; no barrier) ----
#pragma unroll
  for (int d = 0; d < 2; ++d)
#pragma unroll
    for (int nt = 0; nt < 4; ++nt)
#pragma unroll
      for (int r = 0; r < 4; ++r) {
        const int o   = nt * 16 + li;
        const int row = d * 64 + wv * 16 + g * 4 + r;
        Hs[(unsigned)((o >> 3) * 128 + row) * 8 + (o & 7)] = f2bf(lrelu(acc[d][nt][r]));
      }

  // ---- layer 2: K=64 x N=32 (reads wave's own Hs rows) ----
  f32x4 acc2[2][2];
#pragma unroll
  for (int nt = 0; nt < 2; ++nt) {
    const float bv = wtab[OFF_B2F + nt * 16 + li];
    acc2[0][nt] = (f32x4){bv, bv, bv, bv};
    acc2[1][nt] = acc2[0][nt];
  }
#pragma unroll
  for (int kh = 0; kh < 2; ++kh) {
    const bf16x8 a0 = *(const bf16x8*)&Hs[(unsigned)((kh * 4 + g) * 128 + 0 * 64 + pxl) * 8];
    const bf16x8 a1 = *(const bf16x8*)&Hs[(unsigned)((kh * 4 + g) * 128 + 1 * 64 + pxl) * 8];
#pragma unroll
    for (int nt = 0; nt < 2; ++nt) {
      const bf16x8 b = *(const bf16x8*)&w2bu[(unsigned)((kh * 2 + nt) * 64 + lane) * 8];
      acc2[0][nt] = __builtin_amdgcn_mfma_f32_16x16x32_bf16(a0, b, acc2[0][nt], 0, 0, 0);
      acc2[1][nt] = __builtin_amdgcn_mfma_f32_16x16x32_bf16(a1, b, acc2[1][nt], 0, 0, 0);
    }
  }

  // ---- layer 3 + 16-lane reduce + in-wave softmax (b3 cancels) ----
  const float w3a = wtab[OFF_W3F + li];
  const float w3b = wtab[OFF_W3F + 16 + li];
  float wt0[4], wt1[4];
#pragma unroll
  for (int r = 0; r < 4; ++r) {
    float p0 = w3a * lrelu(acc2[0][0][r]) + w3b * lrelu(acc2[0][1][r]);
    float p1 = w3a * lrelu(acc2[1][0][r]) + w3b * lrelu(acc2[1][1][r]);
    p0 += __shfl_xor(p0, 1); p0 += __shfl_xor(p0, 2);
    p0 += __shfl_xor(p0, 4); p0 += __shfl_xor(p0, 8);
    p1 += __shfl_xor(p1, 1); p1 += __shfl_xor(p1, 2);
    p1 += __shfl_xor(p1, 4); p1 += __shfl_xor(p1, 8);
    wt0[r] = 1.f / (1.f + expf(p1 - p0));   // px_local = wv*16 + g*4 + r
    wt1[r] = 1.f / (1.f + expf(p0 - p1));
  }

  // ---- wt distribution: lane's px (index li) owned by group li>>2, slot li&3 ----
  const int src = (li >> 2) << 4;
  float a0 = __shfl(wt0[0], src), b0 = __shfl(wt1[0], src);
  float a1 = __shfl(wt0[1], src), b1v = __shfl(wt1[1], src);
  float a2 = __shfl(wt0[2], src), b2v = __shfl(wt1[2], src);
  float a3 = __shfl(wt0[3], src), b3v = __shfl(wt1[3], src);
  const int rs = li & 3;
  const float w0  = (rs == 0) ? a0 : (rs == 1) ? a1 : (rs == 2) ? a2 : a3;
  const float w1v = (rs == 0) ? b0 : (rs == 1) ? b1v : (rs == 2) ? b2v : b3v;

  // ---- f-store from the bf16 A-fragment registers ----
#pragma unroll
  for (int kh = 0; kh < 2; ++kh)
#pragma unroll
    for (int j = 0; j < 4; ++j) {
      const int k = kh * 16 + g * 4 + j;        // channel-pair index; c0=2k, c1=2k+1
      const unsigned ua = xb[0][kh].u[j];       // (c0,d0) lo | (c1,d0) hi
      const unsigned ub = xb[1][kh].u[j];       // (c0,d1) lo | (c1,d1) hi
      uint2 pk;
      pk.x = pack2bf(bflo(ua) * w0, bflo(ub) * w1v);
      pk.y = pack2bf(bfhi(ua) * w0, bfhi(ub) * w1v);
      *(uint2*)&dst[(((size_t)n * 32 + k) * HW + px) * 4] = pk;
    }
}

// ---------------- pass 2: pure memory — out = max(f0, bilinear(rot(f1))) ----------------
__global__ __launch_bounds__(256)
void gather_max_kernel(const unsigned short* __restrict__ f0b,
                       const unsigned short* __restrict__ f1b,
                       const float* __restrict__ tp,
                       float* __restrict__ out) {
  // bijective XCD swizzle over 550 tiles (q=68, r=6)
  const int orig = blockIdx.x;
  const int xcd = orig & 7, idx = orig >> 3;
  const int tile = (xcd < 6 ? xcd * 69 : 6 * 69 + (xcd - 6) * 68) + idx;

  const int tix = threadIdx.x;
  const int px  = tix & 63;
  const int q   = tix >> 6;
  const int n   = blockIdx.y;
  const int hw  = tile * 64 + px;
  const int h   = hw / 176;
  const int w   = hw - h * 176;

  const float thp = tp[n * 2 + 0], thc = tp[n * 2 + 1];
  const float gx = 0.2f + 0.4f * (float)w;
  const float gy = -39.8f + 0.4f * (float)h;
  const float c1 = cosf(thc),  s1v = sinf(thc);
  const float p1x = gx * c1 - gy * s1v;
  const float p1y = gx * s1v + gy * c1;
  const float c2 = cosf(-thp), s2v = sinf(-thp);
  const float p2x = p1x * c2 - p1y * s2v;
  const float p2y = p1x * s2v + p1y * c2;
  const float xi = p2x / 0.05f / 8.f;
  const float yi = (p2y - (-40.f)) / 0.05f / 8.f;

  const float xf = floorf(xi), yf = floorf(yi);
  const int x0i = (int)xf, y0i = (int)yf;
  const int x0c = min(max(x0i,     0), 175);
  const int x1c = min(max(x0i + 1, 0), 175);
  const int y0c = min(max(y0i,     0), 199);
  const int y1c = min(max(y0i + 1, 0), 199);
  const float x0f = (float)x0c, x1f = (float)x1c;
  const float y0f = (float)y0c, y1f = (float)y1c;
  const float wa = (x1f - xi) * (y1f - yi);
  const float wb = (x1f - xi) * (yi - y0f);
  const float wc = (xi - x0f) * (y1f - yi);
  const float wd = (xi - x0f) * (yi - y0f);
  const int ta = y0c * 176 + x0c, tb = y1c * 176 + x0c;
  const int tc = y0c * 176 + x1c, td = y1c * 176 + x1c;

#pragma unroll
  for (int i = 0; i < 8; ++i) {
    const int k = q * 8 + i;
    const int cd0 = k * 4;
    const unsigned short* fp1 = f1b + ((size_t)n * 32 + k) * HW * 4;
    const uint2 Ia = *(const uint2*)(fp1 + (size_t)ta * 4);
    const uint2 Ib = *(const uint2*)(fp1 + (size_t)tb * 4);
    const uint2 Ic = *(const uint2*)(fp1 + (size_t)tc * 4);
    const uint2 Id = *(const uint2*)(fp1 + (size_t)td * 4);
    float4 sv;
    sv.x = bflo(Ia.x) * wa + bflo(Ib.x) * wb + bflo(Ic.x) * wc + bflo(Id.x) * wd;
    sv.y = bfhi(Ia.x) * wa + bfhi(Ib.x) * wb + bfhi(Ic.x) * wc + bfhi(Id.x) * wd;
    sv.z = bflo(Ia.y) * wa + bflo(Ib.y) * wb + bflo(Ic.y) * wc + bflo(Id.y) * wd;
    sv.w = bfhi(Ia.y) * wa + bfhi(Ib.y) * wb + bfhi(Ic.y) * wc + bfhi(Id.y) * wd;

    const uint2 F0 = *(const uint2*)(f0b + (((size_t)n * 32 + k) * HW + hw) * 4);

    float* op = out + ((size_t)n * CD + cd0) * HW + hw;
    op[0]              = fmaxf(bflo(F0.x), sv.x);
    op[HW]             = fmaxf(bfhi(F0.x), sv.y);
    op[2 * (size_t)HW] = fmaxf(bflo(F0.y), sv.z);
    op[3 * (size_t)HW] = fmaxf(bfhi(F0.y), sv.w);
  }
}

extern "C" void kernel_launch(void* const* d_in, const int* in_sizes, int n_in,
                              void* d_out, int out_size, void* d_ws, size_t ws_size,
                              hipStream_t stream) {
  const float* x0  = (const float*)d_in[0];
  const float* x1  = (const float*)d_in[1];
  const float* tp  = (const float*)d_in[2];
  const float* w1  = (const float*)d_in[3];
  const float* b1  = (const float*)d_in[4];
  const float* g1  = (const float*)d_in[5];
  const float* be1 = (const float*)d_in[6];
  const float* w2  = (const float*)d_in[7];
  const float* b2  = (const float*)d_in[8];
  const float* g2  = (const float*)d_in[9];
  const float* be2 = (const float*)d_in[10];
  const float* w3  = (const float*)d_in[11];
  const float* b3  = (const float*)d_in[12];
  float* ws = (float*)d_ws;
  unsigned short* f0b = (unsigned short*)(ws + OFF_F0B);
  unsigned short* f1b = (unsigned short*)(ws + OFF_F1B);

  setup_kernel<<<2233, 256, 0, stream>>>(w1, b1, g1, be1, w2, b2, g2, be2, w3, b3, ws);

  dim3 g1d(550, 4, 2);   // 64 px per block (4 waves), n, input
  mlp_kernel<<<g1d, 256, 0, stream>>>(x0, x1, ws, f0b, f1b);

  dim3 g2d(550, 4);      // 64 px x 4 channel-quarters, n
  gather_max_kernel<<<g2d, 256, 0, stream>>>(f0b, f1b, tp, (float*)d_out);
}